// Round 5
// baseline (350.576 us; speedup 1.0000x reference)
//
#include <hip/hip_runtime.h>
#include <hip/hip_bf16.h>
#include <cstddef>

// K=2048, B=4, D=5, ATOM=125, BOND=12, HID=125, OUT=40
// NOFF = [0, 2048, 10240, 43008, 175104, 699392]
// BOFF = [0, 8192, 40960, 172032, 696320]
//
// FULLY-FUSED tree, conservative build: every numeric/layout component is the
// round-3-validated pattern; only the (triple-verified) pass-chain is new.
//  - one block per root: leaf 2x128 -> d3 2x128 -> d2 64 -> d1 16 -> d0 4 -> out
//  - child outputs live in LDS, plain [row][48] bf16 row-major
//  - layer1: 2x mfma_f32_16x16x32_bf16 (W split hi/lo = fp32-grade W; X bf16)
//  - layer2 from registers, W2 frag-packed (r3-validated mapping)
//  - k' layout (192): [0,125) msg, [125,128) 0, [128,140) bond, [140,144) 0,
//    [144,184) child, [184,192) 0  (child 8-aligned -> direct LDS B-reads)
//  - per chunk: [stage(kc)][sync][issue(kc+1) global->regs][MFMA(kc)][sync]
//    (loads' latency spans the MFMA phase; single-buffered LDS is safe)

typedef __attribute__((ext_vector_type(8))) short short8;
typedef __attribute__((ext_vector_type(4))) float f32x4;
typedef __attribute__((ext_vector_type(4))) unsigned int v4u;

static constexpr int HID = 125, OUT = 40;

template <int N> struct ic { static constexpr int v = N; };

__device__ __forceinline__ unsigned short f2bf(float x) {
    __hip_bfloat16 b = __float2bfloat16(x);  // RNE
    return __builtin_bit_cast(unsigned short, b);
}
__device__ __forceinline__ float bf2f(unsigned short h) {
    return __bfloat162float(__builtin_bit_cast(__hip_bfloat16, h));
}
__device__ __forceinline__ unsigned int pack2(unsigned short a, unsigned short b) {
    return (unsigned int)a | ((unsigned int)b << 16);
}

// W1 hi/lo planes: [128 hid][192 k'] bf16, k' remapped per layout above.
__global__ void prep_w1(const float* __restrict__ W1,
                        unsigned short* __restrict__ w1h,
                        unsigned short* __restrict__ w1l) {
    int idx = blockIdx.x * 256 + threadIdx.x;
    if (idx >= 128 * 192) return;
    int hid = idx / 192, kp = idx % 192;
    int k = (kp < 125) ? kp
          : (kp >= 128 && kp < 140) ? kp - 3
          : (kp >= 144 && kp < 184) ? kp - 7 : -1;
    float v = (k >= 0 && hid < HID) ? W1[(size_t)k * HID + hid] : 0.f;
    unsigned short h = f2bf(v);
    unsigned short l = f2bf(v - bf2f(h));
    w1h[idx] = h;
    w1l[idx] = l;
}

// W2 frag-packed (layer2 B), round-3-validated mapping:
// frag fr = kt*3+qt; lane ln; elem j: hid = kt*32 + 16*(j>>2) + (ln>>4)*4 + (j&3),
// q = qt*16 + (ln&15). 4 u32 per (fr,lane).
__global__ void prep_w2(const float* __restrict__ W2, unsigned int* __restrict__ w2f) {
    int t = threadIdx.x;
    for (int task = t; task < 12 * 64; task += 256) {
        int ln = task & 63, fr = task >> 6;
        int kt = fr / 3, qt = fr % 3;
        int q = qt * 16 + (ln & 15);
        unsigned int w[4];
#pragma unroll
        for (int jp = 0; jp < 4; jp++) {
            unsigned short e[2];
#pragma unroll
            for (int s = 0; s < 2; s++) {
                int j = jp * 2 + s;
                int hid = kt * 32 + ((j >> 2) << 4) + ((ln >> 4) << 2) + (j & 3);
                float v = (hid < HID && q < OUT) ? W2[(size_t)hid * OUT + q] : 0.f;
                e[s] = f2bf(v);
            }
            w[jp] = pack2(e[0], e[1]);
        }
        v4u val = {w[0], w[1], w[2], w[3]};
        ((v4u*)w2f)[fr * 64 + ln] = val;
    }
}

struct Desc {
    int msgRow;   // node row of (local row 0's parent) / leaf row 0
    int bondRow;  // edge row of local row 0
    int leaf;
};

__global__ void __launch_bounds__(256, 2)
tree_mlp(const float* __restrict__ node_msg, const float* __restrict__ bonds,
         const unsigned short* __restrict__ w1h, const unsigned short* __restrict__ w1l,
         const unsigned int* __restrict__ w2f,
         const float* __restrict__ b1, const float* __restrict__ b2,
         float* __restrict__ out) {
    __shared__ __align__(16) unsigned short Xh[128 * 40];   // [row][40], 80B stride
    __shared__ __align__(16) unsigned short Wh[128 * 40];   // [hid][40]
    __shared__ __align__(16) unsigned short Wl[128 * 40];
    __shared__ __align__(16) unsigned short lout[128 * 48]; // child buf, [row][48]
    __shared__ __align__(16) unsigned short d3o[64 * 48];
    __shared__ __align__(16) unsigned short d2o[16 * 48];
    __shared__ __align__(16) unsigned short d1o[16 * 48];
    __shared__ __align__(16) unsigned short zs[8];          // zero 16B slot

    const int tid = threadIdx.x;
    const int lane = tid & 63;
    const int wv = tid >> 6;
    const int l15 = tid & 15;
    const int l16 = (tid >> 4) & 3;
    const int c4 = tid & 3;      // X stager col-group (8 cols of 32-chunk)
    const int rw = tid >> 2;     // X stager row 0..63 (and +64)
    const int wr_ = tid >> 1;    // W stager hid row 0..127
    const int whf = tid & 1;     // W stager half (16 k' each)
    const int b = blockIdx.x;

    // zero child buffers (stale-read insurance; d1o rows>=4 strictly needs it)
    for (int i = tid; i < 64 * 48; i += 256) d3o[i] = 0;
    for (int i = tid; i < 16 * 48; i += 256) { d2o[i] = 0; d1o[i] = 0; }
    if (tid < 8) zs[tid] = 0;

    const Desc dL0{175104 + 256 * b, 0, 1};
    const Desc dL1{175104 + 256 * b + 128, 0, 1};
    const Desc dD0{43008 + 64 * b, 172032 + 256 * b, 0};
    const Desc dD1{43008 + 64 * b + 32, 172032 + 256 * b + 128, 0};
    const Desc dd2{10240 + 16 * b, 40960 + 64 * b, 0};
    const Desc dd1{2048 + 4 * b, 8192 + 16 * b, 0};
    const Desc dd0{b, 4 * b, 0};

    float xr[8][2];          // in-flight X chunk (cols c4*8..+7 of rows rw, rw+64)
    v4u wrh0, wrh1, wrl0, wrl1;  // in-flight W chunk

    // ---- issue global loads for chunk cc into registers ----
    auto issue = [&](const Desc& d, int cc, int Rv) {
        if (cc <= 4) {
#pragma unroll
            for (int p = 0; p < 2; p++) {
                int row = rw + 64 * p;
                bool ok = row < Rv;
                if (cc < 4) {
                    int mr = d.leaf ? row : (row >> 2);
                    const float* mp = node_msg + (size_t)(d.msgRow + mr) * 125;
#pragma unroll
                    for (int i = 0; i < 8; i++) {
                        int f = cc * 32 + c4 * 8 + i;
                        xr[i][p] = (ok && f < 125) ? mp[f] : 0.f;
                    }
                } else {  // cc==4: bond cols (c4<2), zeros otherwise
                    const float* bp = bonds + (size_t)(d.bondRow + row) * 12;
#pragma unroll
                    for (int i = 0; i < 8; i++) {
                        int c = c4 * 8 + i;
                        xr[i][p] = (ok && c < 12 && !d.leaf) ? bp[c] : 0.f;
                    }
                }
            }
        }
        const unsigned short* gh = w1h + (size_t)wr_ * 192 + cc * 32 + whf * 16;
        const unsigned short* gl = w1l + (size_t)wr_ * 192 + cc * 32 + whf * 16;
        wrh0 = *(const v4u*)gh;       wrh1 = *(const v4u*)(gh + 8);
        wrl0 = *(const v4u*)gl;       wrl1 = *(const v4u*)(gl + 8);
    };

    // ---- write the in-flight chunk registers into LDS ----
    auto stage = [&](int cc) {
        *(v4u*)&Wh[wr_ * 40 + whf * 16] = wrh0;
        *(v4u*)&Wh[wr_ * 40 + whf * 16 + 8] = wrh1;
        *(v4u*)&Wl[wr_ * 40 + whf * 16] = wrl0;
        *(v4u*)&Wl[wr_ * 40 + whf * 16 + 8] = wrl1;
        if (cc < 5 && !(cc == 4 && c4 >= 2)) {  // chunk4 colgrps>=2 come from child buf
#pragma unroll
            for (int p = 0; p < 2; p++) {
                int row = rw + 64 * p;
                v4u val = {pack2(f2bf(xr[0][p]), f2bf(xr[1][p])),
                           pack2(f2bf(xr[2][p]), f2bf(xr[3][p])),
                           pack2(f2bf(xr[4][p]), f2bf(xr[5][p])),
                           pack2(f2bf(xr[6][p]), f2bf(xr[7][p]))};
                *(v4u*)&Xh[row * 40 + c4 * 8] = val;
            }
        }
    };

    // ---- one level pass ----
    // MODE 0: per-row out -> cdst[row][48]; MODE 1: sibling-sum -> cdst[p][48];
    // MODE 2: sibling-sum -> gout (final).
    auto run_pass = [&](auto RC, auto NCC, auto MC, const Desc& cur, const Desc* nxt,
                        int nxtR, const unsigned short* csrc, unsigned short* cdst,
                        int pbase, float* gout) {
        constexpr int R = decltype(RC)::v;
        constexpr int NCv = decltype(NCC)::v;
        constexpr int MODE = decltype(MC)::v;
        constexpr int NT = (R == 128) ? 2 : 1;
        const bool act = (R >= 64) || (wv == 0);

        f32x4 acc[8][NT];
#pragma unroll
        for (int mt = 0; mt < 8; mt++) {
            f32x4 bi;
#pragma unroll
            for (int r = 0; r < 4; r++) {
                int h_ = mt * 16 + l16 * 4 + r;
                bi[r] = (h_ < HID) ? b1[h_] : 0.f;
            }
#pragma unroll
            for (int nt = 0; nt < NT; nt++) acc[mt][nt] = bi;
        }

#pragma unroll 1
        for (int kc = 0; kc < NCv; ++kc) {
            stage(kc);                       // consumes in-flight regs (vmcnt waits here)
            __syncthreads();                 // staged chunk visible
            if (kc + 1 < NCv) issue(cur, kc + 1, R);   // latency spans MFMA below
            else if (nxt) issue(*nxt, 0, nxtR);
            if (act) {
                short8 xf[NT];
#pragma unroll
                for (int nt = 0; nt < NT; ++nt) {
                    int r = ((R == 128) ? wv * 32 + nt * 16 : (R == 64) ? wv * 16 : 0) + l15;
                    const unsigned short* src;
                    if (kc < 4) {
                        src = &Xh[r * 40 + l16 * 8];
                    } else if (kc == 4) {
                        src = (l16 < 2) ? &Xh[r * 40 + l16 * 8]
                                        : &csrc[r * 48 + (l16 - 2) * 8];  // child 0..15
                    } else {
                        src = (l16 < 3) ? &csrc[r * 48 + (l16 + 2) * 8]   // child 16..39
                                        : &zs[0];
                    }
                    xf[nt] = *(const short8*)src;
                }
#pragma unroll
                for (int mt = 0; mt < 8; ++mt) {
                    int hr = mt * 16 + l15;
                    short8 wA = *(const short8*)&Wh[hr * 40 + l16 * 8];
                    short8 wB = *(const short8*)&Wl[hr * 40 + l16 * 8];
#pragma unroll
                    for (int nt = 0; nt < NT; ++nt) {
                        acc[mt][nt] = __builtin_amdgcn_mfma_f32_16x16x32_bf16(wA, xf[nt], acc[mt][nt], 0, 0, 0);
                        acc[mt][nt] = __builtin_amdgcn_mfma_f32_16x16x32_bf16(wB, xf[nt], acc[mt][nt], 0, 0, 0);
                    }
                }
            }
            __syncthreads();                 // reads done; next stage may overwrite
        }

        // ---- layer 2 (registers only; round-3-validated construction) ----
        if (act) {
#pragma unroll
            for (int mt = 0; mt < 8; mt++)
#pragma unroll
                for (int nt = 0; nt < NT; nt++)
#pragma unroll
                    for (int r = 0; r < 4; r++)
                        acc[mt][nt][r] = fmaxf(acc[mt][nt][r], 0.01f * acc[mt][nt][r]);
            float b2v[3];
#pragma unroll
            for (int qt = 0; qt < 3; qt++) {
                int q = qt * 16 + l15;
                b2v[qt] = (q < OUT) ? b2[q] : 0.f;
            }
#pragma unroll
            for (int nt = 0; nt < NT; ++nt) {
                short8 A[4];
#pragma unroll
                for (int kt = 0; kt < 4; kt++) {
                    v4u av = {pack2(f2bf(acc[2 * kt][nt][0]), f2bf(acc[2 * kt][nt][1])),
                              pack2(f2bf(acc[2 * kt][nt][2]), f2bf(acc[2 * kt][nt][3])),
                              pack2(f2bf(acc[2 * kt + 1][nt][0]), f2bf(acc[2 * kt + 1][nt][1])),
                              pack2(f2bf(acc[2 * kt + 1][nt][2]), f2bf(acc[2 * kt + 1][nt][3]))};
                    A[kt] = __builtin_bit_cast(short8, av);
                }
                const int tb = (R == 128) ? wv * 32 + nt * 16 : (R == 64) ? wv * 16 : 0;
#pragma unroll
                for (int qt = 0; qt < 3; ++qt) {
                    f32x4 o = {0.f, 0.f, 0.f, 0.f};
#pragma unroll
                    for (int kt = 0; kt < 4; kt++) {
                        v4u wvv = ((const v4u*)w2f)[(kt * 3 + qt) * 64 + lane];
                        o = __builtin_amdgcn_mfma_f32_16x16x32_bf16(
                            A[kt], __builtin_bit_cast(short8, wvv), o, 0, 0, 0);
                    }
                    int q = qt * 16 + l15;
                    if (MODE == 0) {
                        if (q < OUT) {
#pragma unroll
                            for (int r = 0; r < 4; r++) {
                                int row = tb + l16 * 4 + r;
                                float v = o[r] + b2v[qt];
                                v = fmaxf(v, 0.01f * v);
                                cdst[row * 48 + q] = f2bf(v);
                            }
                        }
                    } else {
                        float s = 0.f;
#pragma unroll
                        for (int r = 0; r < 4; r++) {
                            float v = o[r] + b2v[qt];
                            s += fmaxf(v, 0.01f * v);
                        }
                        if (MODE == 1) {
                            if (q < OUT) {
                                int p = pbase + (tb >> 2) + l16;
                                cdst[p * 48 + q] = f2bf(s);
                            }
                        } else {
                            if (q < OUT && lane < 16) gout[q] = s;  // parent p==0
                        }
                    }
                }
            }
        }
        __syncthreads();
    };

    // ---- prologue: start chunk-0 loads of the first leaf pass ----
    issue(dL0, 0, 128);

    run_pass(ic<128>{}, ic<4>{}, ic<0>{}, dL0, &dD0, 128, lout, lout, 0, nullptr);
    run_pass(ic<128>{}, ic<6>{}, ic<1>{}, dD0, &dL1, 128, lout, d3o, 0, nullptr);
    run_pass(ic<128>{}, ic<4>{}, ic<0>{}, dL1, &dD1, 128, lout, lout, 0, nullptr);
    run_pass(ic<128>{}, ic<6>{}, ic<1>{}, dD1, &dd2, 64, lout, d3o, 32, nullptr);
    run_pass(ic<64>{}, ic<6>{}, ic<1>{}, dd2, &dd1, 16, d3o, d2o, 0, nullptr);
    run_pass(ic<16>{}, ic<6>{}, ic<1>{}, dd1, &dd0, 4, d2o, d1o, 0, nullptr);
    run_pass(ic<4>{}, ic<6>{}, ic<2>{}, dd0, nullptr, 0, d1o, nullptr, 0,
             out + (size_t)b * 40);
}

extern "C" void kernel_launch(void* const* d_in, const int* in_sizes, int n_in,
                              void* d_out, int out_size, void* d_ws, size_t ws_size,
                              hipStream_t stream) {
    const float* node_msg = (const float*)d_in[0];
    const float* bonds = (const float*)d_in[1];
    const float* W1 = (const float*)d_in[2];
    const float* b1 = (const float*)d_in[3];
    const float* W2 = (const float*)d_in[4];
    const float* b2 = (const float*)d_in[5];
    float* out = (float*)d_out;

    char* ws = (char*)d_ws;
    unsigned short* w1h = (unsigned short*)ws;                 // 128*192*2 = 49152 B
    unsigned short* w1l = (unsigned short*)(ws + 49152);       // 49152 B
    unsigned int* w2f = (unsigned int*)(ws + 98304);           // 12*64*16 = 12288 B

    prep_w1<<<96, 256, 0, stream>>>(W1, w1h, w1l);
    prep_w2<<<1, 256, 0, stream>>>(W2, w2f);
    tree_mlp<<<2048, 256, 0, stream>>>(node_msg, bonds, w1h, w1l, w2f, b1, b2, out);
}

// Round 6
// 320.297 us; speedup vs baseline: 1.0945x; 1.0945x over previous
//
#include <hip/hip_runtime.h>
#include <hip/hip_bf16.h>
#include <cstddef>

// K=2048, B=4, D=5, ATOM=125, BOND=12, HID=125, OUT=40
// NOFF = [0, 2048, 10240, 43008, 175104, 699392]
// BOFF = [0, 8192, 40960, 172032, 696320]
//
// Round 6 = round 5 VERBATIM with ONE variable changed: bf16 -> f16.
//  - W1 single f16 plane (no hi/lo split): one mfma_f32_16x16x32_f16 per
//    (mt,nt) instead of two bf16 MFMAs. f16 elementwise precision (4.9e-4)
//    beats the validated bf16-X path (4e-3), so absmax must stay at floor.
//  - All layouts, indices, schedule, barriers IDENTICAL to round 5.
//  - LDS 52.7 KB -> 42.0 KB => 3 blocks/CU.

typedef __attribute__((ext_vector_type(8))) _Float16 h8;
typedef __attribute__((ext_vector_type(4))) float f32x4;
typedef __attribute__((ext_vector_type(4))) unsigned int v4u;

static constexpr int HID = 125, OUT = 40;

template <int N> struct ic { static constexpr int v = N; };

__device__ __forceinline__ unsigned short f2h(float x) {
    _Float16 h = (_Float16)x;
    return __builtin_bit_cast(unsigned short, h);
}
__device__ __forceinline__ unsigned int pkh(float a, float b) {
    return (unsigned int)f2h(a) | ((unsigned int)f2h(b) << 16);
}

// W1 plane: [128 hid][192 k'] f16, k' remapped:
// [0,125) msg, [125,128) 0, [128,140) bond, [140,144) 0, [144,184) child, [184,192) 0
__global__ void prep_w1(const float* __restrict__ W1, unsigned short* __restrict__ w1f) {
    int idx = blockIdx.x * 256 + threadIdx.x;
    if (idx >= 128 * 192) return;
    int hid = idx / 192, kp = idx % 192;
    int k = (kp < 125) ? kp
          : (kp >= 128 && kp < 140) ? kp - 3
          : (kp >= 144 && kp < 184) ? kp - 7 : -1;
    float v = (k >= 0 && hid < HID) ? W1[(size_t)k * HID + hid] : 0.f;
    w1f[idx] = f2h(v);
}

// W2 frag-packed (layer2 B), r3/r5-validated mapping, f16 elements:
// frag fr = kt*3+qt; lane ln; elem j: hid = kt*32 + 16*(j>>2) + (ln>>4)*4 + (j&3),
// q = qt*16 + (ln&15). 4 u32 per (fr,lane).
__global__ void prep_w2(const float* __restrict__ W2, unsigned int* __restrict__ w2f) {
    int t = threadIdx.x;
    for (int task = t; task < 12 * 64; task += 256) {
        int ln = task & 63, fr = task >> 6;
        int kt = fr / 3, qt = fr % 3;
        int q = qt * 16 + (ln & 15);
        unsigned int w[4];
#pragma unroll
        for (int jp = 0; jp < 4; jp++) {
            unsigned short e[2];
#pragma unroll
            for (int s = 0; s < 2; s++) {
                int j = jp * 2 + s;
                int hid = kt * 32 + ((j >> 2) << 4) + ((ln >> 4) << 2) + (j & 3);
                float v = (hid < HID && q < OUT) ? W2[(size_t)hid * OUT + q] : 0.f;
                e[s] = f2h(v);
            }
            w[jp] = (unsigned int)e[0] | ((unsigned int)e[1] << 16);
        }
        v4u val = {w[0], w[1], w[2], w[3]};
        ((v4u*)w2f)[fr * 64 + ln] = val;
    }
}

struct Desc {
    int msgRow;
    int bondRow;
    int leaf;
};

__global__ void __launch_bounds__(256, 3)
tree_mlp(const float* __restrict__ node_msg, const float* __restrict__ bonds,
         const unsigned short* __restrict__ w1f,
         const unsigned int* __restrict__ w2f,
         const float* __restrict__ b1, const float* __restrict__ b2,
         float* __restrict__ out) {
    __shared__ __align__(16) unsigned short Xh[128 * 40];   // [row][40], 80B stride
    __shared__ __align__(16) unsigned short Wh[128 * 40];   // [hid][40]
    __shared__ __align__(16) unsigned short lout[128 * 48]; // child buf, [row][48]
    __shared__ __align__(16) unsigned short d3o[64 * 48];
    __shared__ __align__(16) unsigned short d2o[16 * 48];
    __shared__ __align__(16) unsigned short d1o[16 * 48];
    __shared__ __align__(16) unsigned short zs[8];          // zero 16B slot

    const int tid = threadIdx.x;
    const int lane = tid & 63;
    const int wv = tid >> 6;
    const int l15 = tid & 15;
    const int l16 = (tid >> 4) & 3;
    const int c4 = tid & 3;      // X stager col-group (8 cols of 32-chunk)
    const int rw = tid >> 2;     // X stager row 0..63 (and +64)
    const int wr_ = tid >> 1;    // W stager hid row 0..127
    const int whf = tid & 1;     // W stager half (16 k' each)
    const int b = blockIdx.x;

    // zero child buffers (stale-read insurance)
    for (int i = tid; i < 64 * 48; i += 256) d3o[i] = 0;
    for (int i = tid; i < 16 * 48; i += 256) { d2o[i] = 0; d1o[i] = 0; }
    if (tid < 8) zs[tid] = 0;

    const Desc dL0{175104 + 256 * b, 0, 1};
    const Desc dL1{175104 + 256 * b + 128, 0, 1};
    const Desc dD0{43008 + 64 * b, 172032 + 256 * b, 0};
    const Desc dD1{43008 + 64 * b + 32, 172032 + 256 * b + 128, 0};
    const Desc dd2{10240 + 16 * b, 40960 + 64 * b, 0};
    const Desc dd1{2048 + 4 * b, 8192 + 16 * b, 0};
    const Desc dd0{b, 4 * b, 0};

    float xr[8][2];      // in-flight X chunk (cols c4*8..+7 of rows rw, rw+64)
    v4u wrh0, wrh1;      // in-flight W chunk (16 k' x f16 each)

    // ---- issue global loads for chunk cc into registers ----
    auto issue = [&](const Desc& d, int cc, int Rv) {
        if (cc <= 4) {
#pragma unroll
            for (int p = 0; p < 2; p++) {
                int row = rw + 64 * p;
                bool ok = row < Rv;
                if (cc < 4) {
                    int mr = d.leaf ? row : (row >> 2);
                    const float* mp = node_msg + (size_t)(d.msgRow + mr) * 125;
#pragma unroll
                    for (int i = 0; i < 8; i++) {
                        int f = cc * 32 + c4 * 8 + i;
                        xr[i][p] = (ok && f < 125) ? mp[f] : 0.f;
                    }
                } else {  // cc==4: bond cols (c4<2), zeros otherwise
                    const float* bp = bonds + (size_t)(d.bondRow + row) * 12;
#pragma unroll
                    for (int i = 0; i < 8; i++) {
                        int c = c4 * 8 + i;
                        xr[i][p] = (ok && c < 12 && !d.leaf) ? bp[c] : 0.f;
                    }
                }
            }
        }
        const unsigned short* gh = w1f + (size_t)wr_ * 192 + cc * 32 + whf * 16;
        wrh0 = *(const v4u*)gh;
        wrh1 = *(const v4u*)(gh + 8);
    };

    // ---- write the in-flight chunk registers into LDS ----
    auto stage = [&](int cc) {
        *(v4u*)&Wh[wr_ * 40 + whf * 16] = wrh0;
        *(v4u*)&Wh[wr_ * 40 + whf * 16 + 8] = wrh1;
        if (cc < 5 && !(cc == 4 && c4 >= 2)) {  // chunk4 colgrps>=2 come from child buf
#pragma unroll
            for (int p = 0; p < 2; p++) {
                int row = rw + 64 * p;
                v4u val = {pkh(xr[0][p], xr[1][p]), pkh(xr[2][p], xr[3][p]),
                           pkh(xr[4][p], xr[5][p]), pkh(xr[6][p], xr[7][p])};
                *(v4u*)&Xh[row * 40 + c4 * 8] = val;
            }
        }
    };

    // ---- one level pass ----
    // MODE 0: per-row out -> cdst[row][48]; MODE 1: sibling-sum -> cdst[p][48];
    // MODE 2: sibling-sum -> gout (final).
    auto run_pass = [&](auto RC, auto NCC, auto MC, const Desc& cur, const Desc* nxt,
                        int nxtR, const unsigned short* csrc, unsigned short* cdst,
                        int pbase, float* gout) {
        constexpr int R = decltype(RC)::v;
        constexpr int NCv = decltype(NCC)::v;
        constexpr int MODE = decltype(MC)::v;
        constexpr int NT = (R == 128) ? 2 : 1;
        const bool act = (R >= 64) || (wv == 0);

        f32x4 acc[8][NT];
#pragma unroll
        for (int mt = 0; mt < 8; mt++) {
            f32x4 bi;
#pragma unroll
            for (int r = 0; r < 4; r++) {
                int h_ = mt * 16 + l16 * 4 + r;
                bi[r] = (h_ < HID) ? b1[h_] : 0.f;
            }
#pragma unroll
            for (int nt = 0; nt < NT; nt++) acc[mt][nt] = bi;
        }

#pragma unroll 1
        for (int kc = 0; kc < NCv; ++kc) {
            stage(kc);                       // consumes in-flight regs
            __syncthreads();                 // staged chunk visible
            if (kc + 1 < NCv) issue(cur, kc + 1, R);   // latency spans MFMA below
            else if (nxt) issue(*nxt, 0, nxtR);
            if (act) {
                h8 xf[NT];
#pragma unroll
                for (int nt = 0; nt < NT; ++nt) {
                    int r = ((R == 128) ? wv * 32 + nt * 16 : (R == 64) ? wv * 16 : 0) + l15;
                    const unsigned short* src;
                    if (kc < 4) {
                        src = &Xh[r * 40 + l16 * 8];
                    } else if (kc == 4) {
                        src = (l16 < 2) ? &Xh[r * 40 + l16 * 8]
                                        : &csrc[r * 48 + (l16 - 2) * 8];  // child 0..15
                    } else {
                        src = (l16 < 3) ? &csrc[r * 48 + (l16 + 2) * 8]   // child 16..39
                                        : &zs[0];
                    }
                    xf[nt] = *(const h8*)src;
                }
#pragma unroll
                for (int mt = 0; mt < 8; ++mt) {
                    int hr = mt * 16 + l15;
                    h8 wA = *(const h8*)&Wh[hr * 40 + l16 * 8];
#pragma unroll
                    for (int nt = 0; nt < NT; ++nt)
                        acc[mt][nt] = __builtin_amdgcn_mfma_f32_16x16x32_f16(
                            wA, xf[nt], acc[mt][nt], 0, 0, 0);
                }
            }
            __syncthreads();                 // reads done; next stage may overwrite
        }

        // ---- layer 2 (registers only) ----
        if (act) {
#pragma unroll
            for (int mt = 0; mt < 8; mt++)
#pragma unroll
                for (int nt = 0; nt < NT; nt++)
#pragma unroll
                    for (int r = 0; r < 4; r++)
                        acc[mt][nt][r] = fmaxf(acc[mt][nt][r], 0.01f * acc[mt][nt][r]);
            float b2v[3];
#pragma unroll
            for (int qt = 0; qt < 3; qt++) {
                int q = qt * 16 + l15;
                b2v[qt] = (q < OUT) ? b2[q] : 0.f;
            }
#pragma unroll
            for (int nt = 0; nt < NT; ++nt) {
                h8 A[4];
#pragma unroll
                for (int kt = 0; kt < 4; kt++) {
                    v4u av = {pkh(acc[2 * kt][nt][0], acc[2 * kt][nt][1]),
                              pkh(acc[2 * kt][nt][2], acc[2 * kt][nt][3]),
                              pkh(acc[2 * kt + 1][nt][0], acc[2 * kt + 1][nt][1]),
                              pkh(acc[2 * kt + 1][nt][2], acc[2 * kt + 1][nt][3])};
                    A[kt] = __builtin_bit_cast(h8, av);
                }
                const int tb = (R == 128) ? wv * 32 + nt * 16 : (R == 64) ? wv * 16 : 0;
#pragma unroll
                for (int qt = 0; qt < 3; ++qt) {
                    f32x4 o = {0.f, 0.f, 0.f, 0.f};
#pragma unroll
                    for (int kt = 0; kt < 4; kt++) {
                        v4u wvv = ((const v4u*)w2f)[(kt * 3 + qt) * 64 + lane];
                        o = __builtin_amdgcn_mfma_f32_16x16x32_f16(
                            A[kt], __builtin_bit_cast(h8, wvv), o, 0, 0, 0);
                    }
                    int q = qt * 16 + l15;
                    if (MODE == 0) {
                        if (q < OUT) {
#pragma unroll
                            for (int r = 0; r < 4; r++) {
                                int row = tb + l16 * 4 + r;
                                float v = o[r] + b2v[qt];
                                v = fmaxf(v, 0.01f * v);
                                cdst[row * 48 + q] = f2h(v);
                            }
                        }
                    } else {
                        float s = 0.f;
#pragma unroll
                        for (int r = 0; r < 4; r++) {
                            float v = o[r] + b2v[qt];
                            s += fmaxf(v, 0.01f * v);
                        }
                        if (MODE == 1) {
                            if (q < OUT) {
                                int p = pbase + (tb >> 2) + l16;
                                cdst[p * 48 + q] = f2h(s);
                            }
                        } else {
                            if (q < OUT && lane < 16) gout[q] = s;  // parent p==0
                        }
                    }
                }
            }
        }
        __syncthreads();
    };

    // ---- prologue: start chunk-0 loads of the first leaf pass ----
    issue(dL0, 0, 128);

    run_pass(ic<128>{}, ic<4>{}, ic<0>{}, dL0, &dD0, 128, lout, lout, 0, nullptr);
    run_pass(ic<128>{}, ic<6>{}, ic<1>{}, dD0, &dL1, 128, lout, d3o, 0, nullptr);
    run_pass(ic<128>{}, ic<4>{}, ic<0>{}, dL1, &dD1, 128, lout, lout, 0, nullptr);
    run_pass(ic<128>{}, ic<6>{}, ic<1>{}, dD1, &dd2, 64, lout, d3o, 32, nullptr);
    run_pass(ic<64>{}, ic<6>{}, ic<1>{}, dd2, &dd1, 16, d3o, d2o, 0, nullptr);
    run_pass(ic<16>{}, ic<6>{}, ic<1>{}, dd1, &dd0, 4, d2o, d1o, 0, nullptr);
    run_pass(ic<4>{}, ic<6>{}, ic<2>{}, dd0, nullptr, 0, d1o, nullptr, 0,
             out + (size_t)b * 40);
}

extern "C" void kernel_launch(void* const* d_in, const int* in_sizes, int n_in,
                              void* d_out, int out_size, void* d_ws, size_t ws_size,
                              hipStream_t stream) {
    const float* node_msg = (const float*)d_in[0];
    const float* bonds = (const float*)d_in[1];
    const float* W1 = (const float*)d_in[2];
    const float* b1 = (const float*)d_in[3];
    const float* W2 = (const float*)d_in[4];
    const float* b2 = (const float*)d_in[5];
    float* out = (float*)d_out;

    char* ws = (char*)d_ws;
    unsigned short* w1f = (unsigned short*)ws;            // 128*192*2 = 49152 B
    unsigned int* w2f = (unsigned int*)(ws + 49152);      // 12*64*16 = 12288 B

    prep_w1<<<96, 256, 0, stream>>>(W1, w1f);
    prep_w2<<<1, 256, 0, stream>>>(W2, w2f);
    tree_mlp<<<2048, 256, 0, stream>>>(node_msg, bonds, w1f, w2f, b1, b2, out);
}